// Round 6
// baseline (60.022 us; speedup 1.0000x reference)
//
#include <hip/hip_runtime.h>
#include <hip/hip_bf16.h>

constexpr int BB = 4;
constexpr int SS = 1024;
constexpr int HH = 16;
constexpr int DH = 64;
constexpr int DM = 1024;

using f32x16 = __attribute__((ext_vector_type(16))) float;
using s16x8  = __attribute__((ext_vector_type(8))) short;

__device__ __forceinline__ f32x16 mfma32(s16x8 a, s16x8 b, f32x16 c) {
    return __builtin_amdgcn_mfma_f32_32x32x16_bf16(a, b, c, 0, 0, 0);
}

__device__ __forceinline__ unsigned short bf16bits(float x) {
    union { __hip_bfloat16 h; unsigned short s; } cv;
    cv.h = __float2bfloat16(x);
    return cv.s;
}
__device__ __forceinline__ unsigned pk_bf16(float lo, float hi) {
    return (unsigned)bf16bits(lo) | ((unsigned)bf16bits(hi) << 16);
}

__device__ __forceinline__ float fast_exp2(float x) {
#if __has_builtin(__builtin_amdgcn_exp2f)
    return __builtin_amdgcn_exp2f(x);
#else
    return __expf(x * 0.6931471805599453f);
#endif
}

// ---------------- QKV projection (MFMA) ----------------
// grid 512 = (B*H)*(S/128); block 256 = 4 waves; wave w owns s-rows [w*32, w*32+32).
// Y_m = X_tile[128x64] @ W_m^T + b_m via mfma_f32_32x32x16_bf16.
// ALL outputs staged through swizzled LDS tiles -> 16B coalesced global stores
// (round-5 profile: Q/K 2B-scalar scatter stores were the qkv tail).
__global__ __launch_bounds__(256) void qkv_proj_kernel(
    const float* __restrict__ x,
    const float* __restrict__ Wq, const float* __restrict__ Wk, const float* __restrict__ Wv,
    const float* __restrict__ bq, const float* __restrict__ bk, const float* __restrict__ bv,
    __hip_bfloat16* __restrict__ q_ws, __hip_bfloat16* __restrict__ k_ws,
    __hip_bfloat16* __restrict__ v_ws)
{
    const int bid  = blockIdx.x;
    const int tile = bid & 7;
    const int pair = bid >> 3;
    const int b = pair >> 4, h = pair & 15;
    const int t = threadIdx.x;
    const int w = t >> 6, l = t & 63;
    const int lq = l & 31, hi = l >> 5;
    const int s0 = tile * 128;

    __shared__ __align__(16) char Xs[16384];   // X stage [128 s][128B], then Q out
    __shared__ __align__(16) char Kt[16384];   // K out  [128 s][128B]
    __shared__ __align__(16) char Vt[16384];   // V out transposed [64 e][256B]

    // stage X (fp32 -> bf16), 16B global loads, swizzled 8B LDS writes
    {
        const float* xb = x + (size_t)(b * SS + s0) * DM + h * DH;
        #pragma unroll
        for (int i = 0; i < 8; ++i) {
            const int c  = t + 256 * i;
            const int r  = c >> 4, cw = c & 15;
            float4 v4 = *reinterpret_cast<const float4*>(xb + (size_t)r * DM + cw * 4);
            uint2 p;
            p.x = pk_bf16(v4.x, v4.y);
            p.y = pk_bf16(v4.z, v4.w);
            *reinterpret_cast<uint2*>(Xs + r * 128 + ((cw * 8) ^ ((r & 7) << 4))) = p;
        }
    }
    __syncthreads();

    // A-fragments: X[w*32+lq][16s+8hi+0..7], reused for all 3 matrices
    const int arow = w * 32 + lq;
    const int asw  = (arow & 7) << 4;
    s16x8 af[4];
    #pragma unroll
    for (int s = 0; s < 4; ++s)
        af[s] = *reinterpret_cast<const s16x8*>(Xs + arow * 128 + ((s * 32 + hi * 16) ^ asw));
    __syncthreads();   // Xs now free for reuse as Q-out tile

    #pragma unroll
    for (int m = 0; m < 3; ++m) {
        const float* Wm = (m == 0) ? Wq : (m == 1) ? Wk : Wv;
        const float* bm = (m == 0) ? bq : (m == 1) ? bk : bv;

        f32x16 a0, a1;
        #pragma unroll
        for (int r = 0; r < 16; ++r) { a0[r] = 0.0f; a1[r] = 0.0f; }

        #pragma unroll
        for (int s = 0; s < 4; ++s) {
            // B-frag: B[k=16s+8hi+j][col=e] = W[e][16s+8hi+j]; e = lq / 32+lq
            const float* wp0 = Wm + (size_t)(h * DH + lq) * DH + s * 16 + hi * 8;
            const float* wp1 = wp0 + 32 * DH;
            float4 wa0 = reinterpret_cast<const float4*>(wp0)[0];
            float4 wb0 = reinterpret_cast<const float4*>(wp0)[1];
            float4 wa1 = reinterpret_cast<const float4*>(wp1)[0];
            float4 wb1 = reinterpret_cast<const float4*>(wp1)[1];
            union { unsigned u[4]; s16x8 v; } bf0, bf1;
            bf0.u[0] = pk_bf16(wa0.x, wa0.y); bf0.u[1] = pk_bf16(wa0.z, wa0.w);
            bf0.u[2] = pk_bf16(wb0.x, wb0.y); bf0.u[3] = pk_bf16(wb0.z, wb0.w);
            bf1.u[0] = pk_bf16(wa1.x, wa1.y); bf1.u[1] = pk_bf16(wa1.z, wa1.w);
            bf1.u[2] = pk_bf16(wb1.x, wb1.y); bf1.u[3] = pk_bf16(wb1.z, wb1.w);
            a0 = mfma32(af[s], bf0.v, a0);
            a1 = mfma32(af[s], bf1.v, a1);
        }

        const float bias0 = bm[h * DH + lq];
        const float bias1 = bm[h * DH + 32 + lq];

        if (m < 2) {
            // [s][d] tile: for fixed r, 32 lanes of a half write one row's 64B -> conflict-free
            char* T = (m == 0) ? Xs : Kt;
            #pragma unroll
            for (int r = 0; r < 16; ++r) {
                const int row = w * 32 + (r & 3) + 8 * (r >> 2) + 4 * hi;
                const int sw  = (row & 7) << 4;
                *reinterpret_cast<unsigned short*>(T + row * 128 + ((lq * 2) ^ sw)) =
                    bf16bits(a0[r] + bias0);
                *reinterpret_cast<unsigned short*>(T + row * 128 + (((32 + lq) * 2) ^ sw)) =
                    bf16bits(a1[r] + bias1);
            }
        } else {
            // Vt[e][s]: regs 4g..4g+3 are s-rows w*32 + 8g + 4hi + 0..3 -> 8B packs
            #pragma unroll
            for (int g = 0; g < 4; ++g) {
                const int off = w * 64 + g * 16 + hi * 8;
                uint2 p0, p1;
                p0.x = pk_bf16(a0[4*g+0] + bias0, a0[4*g+1] + bias0);
                p0.y = pk_bf16(a0[4*g+2] + bias0, a0[4*g+3] + bias0);
                p1.x = pk_bf16(a1[4*g+0] + bias1, a1[4*g+1] + bias1);
                p1.y = pk_bf16(a1[4*g+2] + bias1, a1[4*g+3] + bias1);
                *reinterpret_cast<uint2*>(Vt + lq * 256 + (off ^ ((lq & 7) << 4))) = p0;
                *reinterpret_cast<uint2*>(Vt + (32 + lq) * 256 + (off ^ (((32 + lq) & 7) << 4))) = p1;
            }
        }
    }
    __syncthreads();

    // batched coalesced drains: Q,K ([128][128B]) and V ([64][256B])
    #pragma unroll
    for (int i = 0; i < 4; ++i) {
        const int c   = t + 256 * i;
        const int row = c >> 3, cc = c & 7;
        const int off = row * 128 + ((cc * 16) ^ ((row & 7) << 4));
        s16x8 qv = *reinterpret_cast<const s16x8*>(Xs + off);
        *reinterpret_cast<s16x8*>(q_ws + ((size_t)pair * SS + s0 + row) * DH + cc * 8) = qv;
        s16x8 kv = *reinterpret_cast<const s16x8*>(Kt + off);
        *reinterpret_cast<s16x8*>(k_ws + ((size_t)pair * SS + s0 + row) * DH + cc * 8) = kv;
    }
    #pragma unroll
    for (int i = 0; i < 4; ++i) {
        const int c   = t + 256 * i;
        const int row = c >> 4, cc = c & 15;
        s16x8 vv = *reinterpret_cast<const s16x8*>(
            Vt + row * 256 + ((cc * 16) ^ ((row & 7) << 4)));
        *reinterpret_cast<s16x8*>(v_ws + ((size_t)pair * DH + row) * SS + s0 + cc * 8) = vv;
    }
}

// ---------------- Flash attention (32x32 swapped-QK^T, in-register softmax) ----------------
// grid 512 = 64 pairs x 8 q-tiles (XCD-swizzled); block 256 = 4 waves x 32 q-rows.
// Round-6 changes: double-buffered K/V LDS (1 barrier/tile), prefetch issued BEFORE
// compute (T14), log-depth tree reductions for max and sum (was 31/32-deep serial).
__global__ __launch_bounds__(256) void attn_kernel(
    const __hip_bfloat16* __restrict__ q_ws,
    const __hip_bfloat16* __restrict__ k_ws,
    const __hip_bfloat16* __restrict__ v_ws,
    float* __restrict__ out)
{
    const int bid  = blockIdx.x;
    const int lbid = (bid & 7) * 64 + (bid >> 3);   // XCD-aware swizzle (512 % 8 == 0)
    const int qt   = lbid & 7;
    const int pair = lbid >> 3;
    const int b = pair >> 4, h = pair & 15;
    const int t = threadIdx.x;
    const int w = t >> 6, l = t & 63;
    const int lq = l & 31, hi = l >> 5;

    __shared__ __align__(16) char Kl[2][8192];
    __shared__ __align__(16) char Vl[2][8192];

    // Q fragments (B-operand): lane holds Q[q=lq][16*s5 + 8*hi + 0..7]
    const __hip_bfloat16* qp = q_ws + ((size_t)pair * SS + qt * 128 + w * 32 + lq) * DH + hi * 8;
    s16x8 qf[4];
    #pragma unroll
    for (int s5 = 0; s5 < 4; ++s5)
        qf[s5] = *reinterpret_cast<const s16x8*>(qp + s5 * 16);

    // staging: chunk u (16B) -> LDS chunk u ^ ((u>>3)&7); source stays linear/coalesced
    const int u0 = t, u1 = t + 256;
    const __hip_bfloat16* kb = k_ws + (size_t)pair * SS * DH;
    const __hip_bfloat16* vb = v_ws + (size_t)pair * DH * SS;
    const int ksw0 = (u0 ^ ((u0 >> 3) & 7)) * 16;
    const int ksw1 = (u1 ^ ((u1 >> 3) & 7)) * 16;
    const size_t voff0 = (size_t)(u0 >> 3) * SS + (u0 & 7) * 8;
    const size_t voff1 = (size_t)(u1 >> 3) * SS + (u1 & 7) * 8;

    // prologue: tile 0 -> buf 0
    {
        s16x8 k0 = *reinterpret_cast<const s16x8*>(kb + u0 * 8);
        s16x8 k1 = *reinterpret_cast<const s16x8*>(kb + u1 * 8);
        s16x8 v0 = *reinterpret_cast<const s16x8*>(vb + voff0);
        s16x8 v1 = *reinterpret_cast<const s16x8*>(vb + voff1);
        *reinterpret_cast<s16x8*>(Kl[0] + ksw0) = k0;
        *reinterpret_cast<s16x8*>(Kl[0] + ksw1) = k1;
        *reinterpret_cast<s16x8*>(Vl[0] + ksw0) = v0;
        *reinterpret_cast<s16x8*>(Vl[0] + ksw1) = v1;
    }
    __syncthreads();

    f32x16 o0, o1;
    #pragma unroll
    for (int r = 0; r < 16; ++r) { o0[r] = 0.0f; o1[r] = 0.0f; }
    float m_run = -3.0e38f, lsum = 0.0f;
    const float cml = 0.18033688011112042f;  // log2(e)/8 : folds 1/sqrt(64) + exp2 domain

    const int kbase0 = lq * 128;
    const int kbase1 = (32 + lq) * 128;
    const int swz = (lq & 7) << 4;

    int p = 0;
    s16x8 kr0, kr1, vr0, vr1;
    for (int kt = 0; kt < 16; ++kt) {
        if (kt < 15) {                             // T14: issue next-tile loads before compute
            kr0 = *reinterpret_cast<const s16x8*>(kb + (kt + 1) * 4096 + u0 * 8);
            kr1 = *reinterpret_cast<const s16x8*>(kb + (kt + 1) * 4096 + u1 * 8);
            vr0 = *reinterpret_cast<const s16x8*>(vb + voff0 + (kt + 1) * 64);
            vr1 = *reinterpret_cast<const s16x8*>(vb + voff1 + (kt + 1) * 64);
        }
        const char* Kp = Kl[p];
        const char* Vp = Vl[p];

        // QK^T (swapped): sc[g] = K_g . Q^T   (4 chained k=16 steps over d=64)
        f32x16 sc0, sc1;
        #pragma unroll
        for (int r = 0; r < 16; ++r) { sc0[r] = 0.0f; sc1[r] = 0.0f; }
        #pragma unroll
        for (int s5 = 0; s5 < 4; ++s5) {
            const int co = (2 * s5 + hi) << 4;
            s16x8 ka = *reinterpret_cast<const s16x8*>(Kp + kbase0 + (co ^ swz));
            sc0 = mfma32(ka, qf[s5], sc0);
        }
        #pragma unroll
        for (int s5 = 0; s5 < 4; ++s5) {
            const int co = (2 * s5 + hi) << 4;
            s16x8 ka = *reinterpret_cast<const s16x8*>(Kp + kbase1 + (co ^ swz));
            sc1 = mfma32(ka, qf[s5], sc1);
        }

        // online softmax: tree max (depth 5), exp2, tree sum (depth 5)
        float tm[16];
        #pragma unroll
        for (int r = 0; r < 16; ++r) tm[r] = fmaxf(sc0[r], sc1[r]);
        #pragma unroll
        for (int s = 8; s >= 1; s >>= 1)
            #pragma unroll
            for (int r = 0; r < 8; ++r)
                if (r < s) tm[r] = fmaxf(tm[r], tm[r + s]);
        float mx = fmaxf(tm[0], __shfl_xor(tm[0], 32));

        if (!__all((mx - m_run) * cml <= 8.0f)) {  // T13 defer-rescale (P bounded by 2^8)
            float mnew  = fmaxf(m_run, mx);
            float alpha = fast_exp2((m_run - mnew) * cml);
            lsum *= alpha;
            #pragma unroll
            for (int r = 0; r < 16; ++r) { o0[r] *= alpha; o1[r] *= alpha; }
            m_run = mnew;
        }
        const float nm = -m_run * cml;
        float ts[16];
        #pragma unroll
        for (int r = 0; r < 16; ++r) {
            sc0[r] = fast_exp2(fmaf(sc0[r], cml, nm));
            sc1[r] = fast_exp2(fmaf(sc1[r], cml, nm));
            ts[r]  = sc0[r] + sc1[r];
        }
        #pragma unroll
        for (int s = 8; s >= 1; s >>= 1)
            #pragma unroll
            for (int r = 0; r < 8; ++r)
                if (r < s) ts[r] += ts[r + s];
        lsum += ts[0] + __shfl_xor(ts[0], 32);

        // P -> A-frag via shfl_xor(32) half-exchange (defined semantics) + PV.
        #pragma unroll
        for (int s5 = 0; s5 < 4; ++s5) {
            const int sb8 = (s5 & 1) * 8;
            unsigned a0, b0, a1, b1;
            if (s5 < 2) {
                a0 = pk_bf16(sc0[sb8 + 0], sc0[sb8 + 1]);
                b0 = pk_bf16(sc0[sb8 + 4], sc0[sb8 + 5]);
                a1 = pk_bf16(sc0[sb8 + 2], sc0[sb8 + 3]);
                b1 = pk_bf16(sc0[sb8 + 6], sc0[sb8 + 7]);
            } else {
                a0 = pk_bf16(sc1[sb8 + 0], sc1[sb8 + 1]);
                b0 = pk_bf16(sc1[sb8 + 4], sc1[sb8 + 5]);
                a1 = pk_bf16(sc1[sb8 + 2], sc1[sb8 + 3]);
                b1 = pk_bf16(sc1[sb8 + 6], sc1[sb8 + 7]);
            }
            const unsigned sa0 = (unsigned)__shfl_xor((int)a0, 32);
            const unsigned sb0 = (unsigned)__shfl_xor((int)b0, 32);
            const unsigned sa1 = (unsigned)__shfl_xor((int)a1, 32);
            const unsigned sb1 = (unsigned)__shfl_xor((int)b1, 32);
            union { unsigned u[4]; s16x8 v; } afr;
            afr.u[0] = hi ? sb0 : a0;   // keys 16s5+8hi+{0,1}
            afr.u[1] = hi ? sb1 : a1;   // keys 16s5+8hi+{2,3}
            afr.u[2] = hi ? b0 : sa0;   // keys 16s5+8hi+{4,5}
            afr.u[3] = hi ? b1 : sa1;   // keys 16s5+8hi+{6,7}
            const int co = (2 * s5 + hi) << 4;
            s16x8 vb0 = *reinterpret_cast<const s16x8*>(Vp + kbase0 + (co ^ swz));
            o0 = mfma32(afr.v, vb0, o0);
            s16x8 vb1 = *reinterpret_cast<const s16x8*>(Vp + kbase1 + (co ^ swz));
            o1 = mfma32(afr.v, vb1, o1);
        }

        if (kt < 15) {                             // write next tile into other buffer
            *reinterpret_cast<s16x8*>(Kl[p ^ 1] + ksw0) = kr0;
            *reinterpret_cast<s16x8*>(Kl[p ^ 1] + ksw1) = kr1;
            *reinterpret_cast<s16x8*>(Vl[p ^ 1] + ksw0) = vr0;
            *reinterpret_cast<s16x8*>(Vl[p ^ 1] + ksw1) = vr1;
        }
        __syncthreads();
        p ^= 1;
    }

    // epilogue: O / lsum ; PV C-layout row = (r&3)+8*(r>>2)+4*hi, col = d = lq (+32 for o1)
    const float inv = 1.0f / lsum;
    #pragma unroll
    for (int r = 0; r < 16; ++r) {
        const int qr = (r & 3) + 8 * (r >> 2) + 4 * hi;
        const float invr = __shfl(inv, qr);
        float* op = out + ((size_t)b * SS + qt * 128 + w * 32 + qr) * DM + h * DH + lq;
        op[0]  = o0[r] * invr;
        op[32] = o1[r] * invr;
    }
}

extern "C" void kernel_launch(void* const* d_in, const int* in_sizes, int n_in,
                              void* d_out, int out_size, void* d_ws, size_t ws_size,
                              hipStream_t stream) {
    const float* x  = (const float*)d_in[0];
    const float* Wq = (const float*)d_in[1];
    const float* Wk = (const float*)d_in[2];
    const float* Wv = (const float*)d_in[3];
    const float* bq = (const float*)d_in[4];
    const float* bk = (const float*)d_in[5];
    const float* bv = (const float*)d_in[6];
    float* out = (float*)d_out;

    __hip_bfloat16* q_ws = (__hip_bfloat16*)d_ws;
    __hip_bfloat16* k_ws = q_ws + (size_t)BB * HH * SS * DH;
    __hip_bfloat16* v_ws = k_ws + (size_t)BB * HH * SS * DH;

    qkv_proj_kernel<<<dim3(BB * HH * (SS / 128)), dim3(256), 0, stream>>>(
        x, Wq, Wk, Wv, bq, bk, bv, q_ws, k_ws, v_ws);
    attn_kernel<<<dim3(BB * HH * (SS / 64 / 2)), dim3(256), 0, stream>>>(
        q_ws, k_ws, v_ws, out);
}